// Round 1
// baseline (124.251 us; speedup 1.0000x reference)
//
#include <hip/hip_runtime.h>
#include <math.h>

// WaveletLayer: (B=4096, S=50, H=256) fp32.
// Per (b,h) row: 3-level db3 wavedec (ptwt reflect-pad) -> per-band filter
// multiply -> waverec -> +residual -> LayerNorm over H.
// One block per b; thread h owns one channel column. LDS holds the 50x256 slab.

#define S_LEN 50
#define H_DIM 256

__device__ constexpr float DLO[6] = {
    0.035226291882100656f, -0.08544127388224149f, -0.13501102001039084f,
    0.4598775021193313f,   0.8068915093133388f,   0.3326705529509569f};
__device__ constexpr float DHI[6] = {
    -0.3326705529509569f,  0.8068915093133388f,  -0.4598775021193313f,
    -0.13501102001039084f, 0.08544127388224149f,  0.035226291882100656f};

// One analysis level. lo[i] = sum_j xp[2i+j]*DLO[5-j] with reflect padding
// (pad left 4, right 4+N%2). All indices compile-time after unroll.
template <int N>
__device__ __forceinline__ void dwt_step(const float* x, float* lo, float* hi) {
  constexpr int M = (N + 5) / 2;
#pragma unroll
  for (int i = 0; i < M; ++i) {
    float sl = 0.f, sh = 0.f;
#pragma unroll
    for (int j = 0; j < 6; ++j) {
      int idx = 2 * i + j - 4;
      idx = (idx < 0) ? -idx : idx;              // reflect left (exclusive)
      idx = (idx >= N) ? (2 * N - 2 - idx) : idx; // reflect right
      const float v = x[idx];
      sl = fmaf(v, DLO[5 - j], sl);
      sh = fmaf(v, DHI[5 - j], sh);
    }
    lo[i] = sl;
    hi[i] = sh;
  }
}

// One synthesis level: rec[p] = out[p+4] of lhs-dilated(2) correlation with
// (DLO,DHI), padding 5. p even -> taps {1,3,5} at t=p/2..p/2+2;
// p odd  -> taps {0,2,4} at t=(p-1)/2.. . Max t = M-1 for all our shapes:
// (M=10,T=16), (M=16,T=27), (M=27,T=50) -> no bounds checks.
template <int M, int T>
__device__ __forceinline__ void idwt_step(const float* lo, const float* hi,
                                          float* rec) {
#pragma unroll
  for (int p = 0; p < T; ++p) {
    const int t = p >> 1;
    float s;
    if ((p & 1) == 0)
      s = lo[t] * DLO[1] + lo[t + 1] * DLO[3] + lo[t + 2] * DLO[5] +
          hi[t] * DHI[1] + hi[t + 1] * DHI[3] + hi[t + 2] * DHI[5];
    else
      s = lo[t] * DLO[0] + lo[t + 1] * DLO[2] + lo[t + 2] * DLO[4] +
          hi[t] * DHI[0] + hi[t + 1] * DHI[2] + hi[t + 2] * DHI[4];
    rec[p] = s;
  }
}

__global__ __launch_bounds__(256, 3) void wavelet_ln_kernel(
    const float* __restrict__ in, const float* __restrict__ f0,
    const float* __restrict__ f1, const float* __restrict__ f2,
    const float* __restrict__ f3, const float* __restrict__ gam,
    const float* __restrict__ bet, float* __restrict__ out) {
  __shared__ float ys[S_LEN * H_DIM];  // 51200 B -> 3 blocks/CU
  const int tid = threadIdx.x;
  const size_t base = (size_t)blockIdx.x * (S_LEN * H_DIM);

  // Stage input slab (B,S,H)-contiguous via float4: 3200 float4 / block.
  const float4* in4 = (const float4*)(in + base);
  float4* ys4 = (float4*)ys;
#pragma unroll
  for (int i = 0; i < 13; ++i) {
    const int idx = i * 256 + tid;
    if (idx < (S_LEN * H_DIM / 4)) ys4[idx] = in4[idx];
  }
  __syncthreads();

  const int h = tid;

  // ---- analysis (all in registers, fully unrolled) ----
  float cA1[27], cD1[27];
  {
    float x[S_LEN];
#pragma unroll
    for (int s = 0; s < S_LEN; ++s) x[s] = ys[s * H_DIM + h];  // 2-way, free
    dwt_step<50>(x, cA1, cD1);
  }  // x dies here -> lower register peak
  float cA2[16], cD2[16];
  dwt_step<27>(cA1, cA2, cD2);
  float cA3[10], cD3[10];
  dwt_step<16>(cA2, cA3, cD3);

  // ---- per-band learned filter multiply (filters are L2-resident, 64 KB) ----
#pragma unroll
  for (int l = 0; l < 10; ++l) {
    cA3[l] *= f0[h * 10 + l];
    cD3[l] *= f1[h * 10 + l];
  }
#pragma unroll
  for (int l = 0; l < 16; ++l) cD2[l] *= f2[h * 16 + l];
#pragma unroll
  for (int l = 0; l < 27; ++l) cD1[l] *= f3[h * 27 + l];

  // ---- synthesis ----
  float r2[16];
  idwt_step<10, 16>(cA3, cD3, r2);
  float r1[27];
  idwt_step<16, 27>(r2, cD2, r1);

  // final level fused with residual: y = x + rec, written in place into ys
#pragma unroll
  for (int p = 0; p < S_LEN; ++p) {
    const int t = p >> 1;
    float s;
    if ((p & 1) == 0)
      s = r1[t] * DLO[1] + r1[t + 1] * DLO[3] + r1[t + 2] * DLO[5] +
          cD1[t] * DHI[1] + cD1[t + 1] * DHI[3] + cD1[t + 2] * DHI[5];
    else
      s = r1[t] * DLO[0] + r1[t + 1] * DLO[2] + r1[t + 2] * DLO[4] +
          cD1[t] * DHI[0] + cD1[t + 1] * DHI[2] + cD1[t + 2] * DHI[4];
    ys[p * H_DIM + h] += s;  // own column only; no cross-thread hazard
  }
  __syncthreads();

  // ---- LayerNorm over H per (b,s): wave w handles s = w, w+4, ... ----
  const int lane = tid & 63;
  const int wv = tid >> 6;
  const float4 g4 = ((const float4*)gam)[lane];
  const float4 b4 = ((const float4*)bet)[lane];
  float* outp = out + base;
  for (int s = wv; s < S_LEN; s += 4) {
    const float4 v = ((const float4*)(ys + s * H_DIM))[lane];
    float sum = v.x + v.y + v.z + v.w;
    float ssq = v.x * v.x + v.y * v.y + v.z * v.z + v.w * v.w;
#pragma unroll
    for (int o = 32; o >= 1; o >>= 1) {
      sum += __shfl_xor(sum, o);
      ssq += __shfl_xor(ssq, o);
    }
    const float mu = sum * (1.0f / H_DIM);
    const float var = fmaxf(ssq * (1.0f / H_DIM) - mu * mu, 0.0f);
    const float rs = rsqrtf(var + 1e-12f);
    float4 o4;
    o4.x = (v.x - mu) * rs * g4.x + b4.x;
    o4.y = (v.y - mu) * rs * g4.y + b4.y;
    o4.z = (v.z - mu) * rs * g4.z + b4.z;
    o4.w = (v.w - mu) * rs * g4.w + b4.w;
    ((float4*)(outp + s * H_DIM))[lane] = o4;  // 16 B/lane coalesced
  }
}

extern "C" void kernel_launch(void* const* d_in, const int* in_sizes, int n_in,
                              void* d_out, int out_size, void* d_ws,
                              size_t ws_size, hipStream_t stream) {
  // setup_inputs() dict order: input_tensor, ln_gamma, ln_beta, filt0..filt3
  const float* in = (const float*)d_in[0];
  const float* gam = (const float*)d_in[1];
  const float* bet = (const float*)d_in[2];
  const float* f0 = (const float*)d_in[3];
  const float* f1 = (const float*)d_in[4];
  const float* f2 = (const float*)d_in[5];
  const float* f3 = (const float*)d_in[6];
  float* out = (float*)d_out;

  wavelet_ln_kernel<<<4096, 256, 0, stream>>>(in, f0, f1, f2, f3, gam, bet,
                                              out);
}

// Round 2
// 120.066 us; speedup vs baseline: 1.0349x; 1.0349x over previous
//
#include <hip/hip_runtime.h>
#include <math.h>

// WaveletLayer: (B=4096, S=50, H=256) fp32.
// Per (b,h) row: 3-level db3 wavedec (ptwt reflect-pad) -> per-band filter
// multiply -> waverec -> +residual -> LayerNorm over H.
// One block per b; thread h owns one channel column.
// Phase 1: 50 coalesced global loads -> full wavelet pipeline in registers ->
//          write rec (small values) as fp16 into a 25.6 KiB LDS slab.
// Phase 2: LN over H per (b,s); y = x(re-read f32, coalesced float4) + rec.

#define S_LEN 50
#define H_DIM 256

typedef __attribute__((ext_vector_type(4))) _Float16 half4;

__device__ constexpr float DLO[6] = {
    0.035226291882100656f, -0.08544127388224149f, -0.13501102001039084f,
    0.4598775021193313f,   0.8068915093133388f,   0.3326705529509569f};
__device__ constexpr float DHI[6] = {
    -0.3326705529509569f,  0.8068915093133388f,  -0.4598775021193313f,
    -0.13501102001039084f, 0.08544127388224149f,  0.035226291882100656f};

// One analysis level. lo[i] = sum_j xp[2i+j]*DLO[5-j] with reflect padding
// (pad left 4, right 4+N%2). All indices compile-time after unroll.
template <int N>
__device__ __forceinline__ void dwt_step(const float* x, float* lo, float* hi) {
  constexpr int M = (N + 5) / 2;
#pragma unroll
  for (int i = 0; i < M; ++i) {
    float sl = 0.f, sh = 0.f;
#pragma unroll
    for (int j = 0; j < 6; ++j) {
      int idx = 2 * i + j - 4;
      idx = (idx < 0) ? -idx : idx;               // reflect left
      idx = (idx >= N) ? (2 * N - 2 - idx) : idx; // reflect right
      const float v = x[idx];
      sl = fmaf(v, DLO[5 - j], sl);
      sh = fmaf(v, DHI[5 - j], sh);
    }
    lo[i] = sl;
    hi[i] = sh;
  }
}

// One synthesis level: p even -> taps {1,3,5} at t=p/2..p/2+2;
// p odd -> taps {0,2,4}. Max t = M-1 for all our shapes -> no bounds checks.
template <int M, int T>
__device__ __forceinline__ void idwt_step(const float* lo, const float* hi,
                                          float* rec) {
#pragma unroll
  for (int p = 0; p < T; ++p) {
    const int t = p >> 1;
    float s;
    if ((p & 1) == 0)
      s = lo[t] * DLO[1] + lo[t + 1] * DLO[3] + lo[t + 2] * DLO[5] +
          hi[t] * DHI[1] + hi[t + 1] * DHI[3] + hi[t + 2] * DHI[5];
    else
      s = lo[t] * DLO[0] + lo[t + 1] * DLO[2] + lo[t + 2] * DLO[4] +
          hi[t] * DHI[0] + hi[t + 1] * DHI[2] + hi[t + 2] * DHI[4];
    rec[p] = s;
  }
}

__global__ __launch_bounds__(256, 4) void wavelet_ln_kernel(
    const float* __restrict__ in, const float* __restrict__ f0,
    const float* __restrict__ f1, const float* __restrict__ f2,
    const float* __restrict__ f3, const float* __restrict__ gam,
    const float* __restrict__ bet, float* __restrict__ out) {
  __shared__ _Float16 recs[S_LEN * H_DIM];  // 25600 B
  const int h = threadIdx.x;
  const size_t base = (size_t)blockIdx.x * (S_LEN * H_DIM);
  const float* __restrict__ inp = in + base;

  // ---- phase 1: wavelet pipeline, all in registers ----
  float cA1[27], cD1[27];
  {
    float x[S_LEN];
#pragma unroll
    for (int s = 0; s < S_LEN; ++s) x[s] = inp[s * H_DIM + h];  // coalesced
    dwt_step<50>(x, cA1, cD1);
  }  // x dies -> lower register peak
  float cA2[16], cD2[16];
  dwt_step<27>(cA1, cA2, cD2);
  float cA3[10], cD3[10];
  dwt_step<16>(cA2, cA3, cD3);

  // per-band learned filter multiply (64.5 KB total, L2-resident)
#pragma unroll
  for (int l = 0; l < 10; ++l) {
    cA3[l] *= f0[h * 10 + l];
    cD3[l] *= f1[h * 10 + l];
  }
#pragma unroll
  for (int l = 0; l < 16; ++l) cD2[l] *= f2[h * 16 + l];
#pragma unroll
  for (int l = 0; l < 27; ++l) cD1[l] *= f3[h * 27 + l];

  float r2[16];
  idwt_step<10, 16>(cA3, cD3, r2);
  float r1[27];
  idwt_step<16, 27>(r2, cD2, r1);

  // final synthesis level -> rec column into fp16 slab (rec is O(0.1))
#pragma unroll
  for (int p = 0; p < S_LEN; ++p) {
    const int t = p >> 1;
    float s;
    if ((p & 1) == 0)
      s = r1[t] * DLO[1] + r1[t + 1] * DLO[3] + r1[t + 2] * DLO[5] +
          cD1[t] * DHI[1] + cD1[t + 1] * DHI[3] + cD1[t + 2] * DHI[5];
    else
      s = r1[t] * DLO[0] + r1[t + 1] * DLO[2] + r1[t + 2] * DLO[4] +
          cD1[t] * DHI[0] + cD1[t + 1] * DHI[2] + cD1[t + 2] * DHI[4];
    recs[p * H_DIM + h] = (_Float16)s;
  }
  __syncthreads();

  // ---- phase 2: LayerNorm over H per (b,s); wave w handles s = w, w+4, ... ----
  const int lane = h & 63;
  const int wv = h >> 6;
  const float4 g4 = ((const float4*)gam)[lane];
  const float4 b4 = ((const float4*)bet)[lane];
  float* outp = out + base;
  for (int s = wv; s < S_LEN; s += 4) {
    const float4 xv = ((const float4*)(inp + s * H_DIM))[lane];  // L2/L3 hit
    const half4 rv = ((const half4*)(recs + s * H_DIM))[lane];
    float4 v;
    v.x = xv.x + (float)rv.x;
    v.y = xv.y + (float)rv.y;
    v.z = xv.z + (float)rv.z;
    v.w = xv.w + (float)rv.w;
    float sum = v.x + v.y + v.z + v.w;
    float ssq = v.x * v.x + v.y * v.y + v.z * v.z + v.w * v.w;
#pragma unroll
    for (int o = 32; o >= 1; o >>= 1) {
      sum += __shfl_xor(sum, o);
      ssq += __shfl_xor(ssq, o);
    }
    const float mu = sum * (1.0f / H_DIM);
    const float var = fmaxf(ssq * (1.0f / H_DIM) - mu * mu, 0.0f);
    const float rs = rsqrtf(var + 1e-12f);
    float4 o4;
    o4.x = (v.x - mu) * rs * g4.x + b4.x;
    o4.y = (v.y - mu) * rs * g4.y + b4.y;
    o4.z = (v.z - mu) * rs * g4.z + b4.z;
    o4.w = (v.w - mu) * rs * g4.w + b4.w;
    ((float4*)(outp + s * H_DIM))[lane] = o4;  // coalesced 16 B/lane
  }
}

extern "C" void kernel_launch(void* const* d_in, const int* in_sizes, int n_in,
                              void* d_out, int out_size, void* d_ws,
                              size_t ws_size, hipStream_t stream) {
  // setup_inputs() dict order: input_tensor, ln_gamma, ln_beta, filt0..filt3
  const float* in = (const float*)d_in[0];
  const float* gam = (const float*)d_in[1];
  const float* bet = (const float*)d_in[2];
  const float* f0 = (const float*)d_in[3];
  const float* f1 = (const float*)d_in[4];
  const float* f2 = (const float*)d_in[5];
  const float* f3 = (const float*)d_in[6];
  float* out = (float*)d_out;

  wavelet_ln_kernel<<<4096, 256, 0, stream>>>(in, f0, f1, f2, f3, gam, bet,
                                              out);
}